// Round 1
// baseline (3106.101 us; speedup 1.0000x reference)
//
#include <hip/hip_runtime.h>

#define H_ 160
#define W_ 160
#define CIN 32
#define COUT 32
#define HW_ (H_ * W_)

// Fused deformable conv v1:
//  stage 1: offset conv (3x3, Cin=32 -> 18 offset channels) per pixel
//  stage 2: bilinear deformable sampling + (Cin*9 x 32) matmul + ReLU
// One thread = one output pixel (all 32 output channels in registers).
// Weights staged in LDS transposed to [tap][cin][cout] so inner-loop reads
// are contiguous float4 wave-uniform broadcasts (conflict-free).
__global__ __launch_bounds__(256, 2) void dcn_fused(
    const float* __restrict__ x,      // (8, 32, 160, 160)
    const float* __restrict__ w_off,  // (18, 32, 3, 3)
    const float* __restrict__ b_off,  // (18,)
    const float* __restrict__ w_dcn,  // (32, 32, 3, 3)
    float* __restrict__ out)          // (8, 32, 160, 160)
{
    __shared__ float wdcn_lds[9 * 32 * 32];  // [tap][c][o]
    __shared__ float woff_lds[9 * 32 * 20];  // [tap][c][j], j padded 18->20
    __shared__ float boff_lds[20];

    const int tid = threadIdx.x;

    // ---- stage weights into LDS (destination-order fill, no races) ----
    for (int d = tid; d < 9 * 32 * 32; d += 256) {
        int tap = d >> 10, c = (d >> 5) & 31, o = d & 31;
        wdcn_lds[d] = w_dcn[(o * 32 + c) * 9 + tap];
    }
    for (int d = tid; d < 9 * 32 * 20; d += 256) {
        int tap = d / 640, c = (d / 20) & 31, j = d % 20;
        woff_lds[d] = (j < 18) ? w_off[(j * 32 + c) * 9 + tap] : 0.0f;
    }
    if (tid < 18) boff_lds[tid] = b_off[tid];
    __syncthreads();

    const int pix = blockIdx.x * 256 + tid;
    const int w = pix % W_;
    const int h = (pix / W_) % H_;
    const int b = pix / HW_;
    const float* __restrict__ xb = x + (size_t)b * CIN * HW_;

    // ---- stage 1: offset conv -> off[0..17] (dy=off[2t], dx=off[2t+1]) ----
    float off[20];
    #pragma unroll
    for (int j = 0; j < 20; ++j) off[j] = 0.0f;

    for (int tap = 0; tap < 9; ++tap) {
        const int yy = h - 1 + tap / 3;
        const int xx = w - 1 + tap % 3;
        const bool valid = (yy >= 0) && (yy < H_) && (xx >= 0) && (xx < W_);
        const int idx = valid ? (yy * W_ + xx) : 0;
        const float* __restrict__ wl = &woff_lds[tap * 32 * 20];
        for (int c = 0; c < 32; ++c) {
            float xv = valid ? xb[c * HW_ + idx] : 0.0f;
            const float4* w4 = (const float4*)(wl + c * 20);
            #pragma unroll
            for (int q = 0; q < 5; ++q) {
                float4 wv = w4[q];
                off[4 * q + 0] = fmaf(xv, wv.x, off[4 * q + 0]);
                off[4 * q + 1] = fmaf(xv, wv.y, off[4 * q + 1]);
                off[4 * q + 2] = fmaf(xv, wv.z, off[4 * q + 2]);
                off[4 * q + 3] = fmaf(xv, wv.w, off[4 * q + 3]);
            }
        }
    }
    #pragma unroll
    for (int j = 0; j < 18; ++j) off[j] += boff_lds[j];

    // ---- stage 2: deformable sampling + matmul ----
    float acc[32];
    #pragma unroll
    for (int o = 0; o < 32; ++o) acc[o] = 0.0f;

    for (int tap = 0; tap < 9; ++tap) {
        const float py = (float)(h - 1 + tap / 3) + off[2 * tap];
        const float px = (float)(w - 1 + tap % 3) + off[2 * tap + 1];
        const float fy0 = floorf(py), fx0 = floorf(px);
        const float wy1 = py - fy0, wx1 = px - fx0;
        const float wy0 = 1.0f - wy1, wx0 = 1.0f - wx1;
        const int y0 = (int)fy0, x0 = (int)fx0;
        const int y1 = y0 + 1, x1 = x0 + 1;
        const bool vy0 = (y0 >= 0) && (y0 < H_);
        const bool vy1 = (y1 >= 0) && (y1 < H_);
        const bool vx0 = (x0 >= 0) && (x0 < W_);
        const bool vx1 = (x1 >= 0) && (x1 < W_);
        const float w00 = (vy0 && vx0) ? wy0 * wx0 : 0.0f;
        const float w01 = (vy0 && vx1) ? wy0 * wx1 : 0.0f;
        const float w10 = (vy1 && vx0) ? wy1 * wx0 : 0.0f;
        const float w11 = (vy1 && vx1) ? wy1 * wx1 : 0.0f;
        const int yc0 = min(max(y0, 0), H_ - 1), yc1 = min(max(y1, 0), H_ - 1);
        const int xc0 = min(max(x0, 0), W_ - 1), xc1 = min(max(x1, 0), W_ - 1);
        const int i00 = yc0 * W_ + xc0, i01 = yc0 * W_ + xc1;
        const int i10 = yc1 * W_ + xc0, i11 = yc1 * W_ + xc1;
        const float* __restrict__ wl = &wdcn_lds[tap * 32 * 32];
        for (int c = 0; c < 32; ++c) {
            const float* __restrict__ xc = xb + c * HW_;
            float v = w00 * xc[i00] + w01 * xc[i01] + w10 * xc[i10] + w11 * xc[i11];
            const float4* w4 = (const float4*)(wl + c * 32);
            #pragma unroll
            for (int q = 0; q < 8; ++q) {
                float4 wv = w4[q];
                acc[4 * q + 0] = fmaf(v, wv.x, acc[4 * q + 0]);
                acc[4 * q + 1] = fmaf(v, wv.y, acc[4 * q + 1]);
                acc[4 * q + 2] = fmaf(v, wv.z, acc[4 * q + 2]);
                acc[4 * q + 3] = fmaf(v, wv.w, acc[4 * q + 3]);
            }
        }
    }

    // ---- epilogue: ReLU + store ----
    float* __restrict__ ob = out + (size_t)b * COUT * HW_ + h * W_ + w;
    #pragma unroll
    for (int o = 0; o < 32; ++o) {
        ob[o * HW_] = fmaxf(acc[o], 0.0f);
    }
}

extern "C" void kernel_launch(void* const* d_in, const int* in_sizes, int n_in,
                              void* d_out, int out_size, void* d_ws, size_t ws_size,
                              hipStream_t stream) {
    const float* x     = (const float*)d_in[0];
    const float* w_off = (const float*)d_in[1];
    const float* b_off = (const float*)d_in[2];
    const float* w_dcn = (const float*)d_in[3];
    float* out = (float*)d_out;

    // 8*160*160 pixels / 256 threads = 800 blocks exactly
    dcn_fused<<<800, 256, 0, stream>>>(x, w_off, b_off, w_dcn, out);
}